// Round 4
// baseline (858.659 us; speedup 1.0000x reference)
//
#include <hip/hip_runtime.h>
#include <hip/hip_bf16.h>
#include <math.h>

#define B_ 2
#define T_ 8
#define M_ 512
#define D_ 1024
#define H_ 1024
#define NC_ 1536
#define KNN 8

typedef __hip_bfloat16 bf16;
typedef short v8s __attribute__((ext_vector_type(8)));   // 8 bf16 (4 VGPRs)
typedef float v4f __attribute__((ext_vector_type(4)));   // MFMA acc

__device__ __forceinline__ float b2f(short s) {
  union { unsigned u; float f; } x; x.u = ((unsigned)(unsigned short)s) << 16; return x.f;
}
__device__ __forceinline__ short f2b(float f) {
  bf16 h = __float2bfloat16(f); return *(short*)&h;
}

// ---------------- async global->LDS 16B (wave-uniform base + lane*16 layout)
__device__ __forceinline__ void async16(const void* g, void* l) {
  __builtin_amdgcn_global_load_lds(
      (const __attribute__((address_space(1))) void*)g,
      (__attribute__((address_space(3))) void*)l, 16, 0, 0);
}

// ---------------- bf16 MFMA tile core: acc += A(128xK) * B(128xK)^T
// LDS tile row-major [128][32] bf16, 16B chunks XOR-swizzled: slot (r,kc) holds
// global k-chunk kc ^ ((r>>1)&3)  -> ds_read_b128 frag reads are 2 lanes/bank (free).
__device__ __forceinline__ void mfma_loop(const bf16* __restrict__ A,
                                          const bf16* __restrict__ Bp,
                                          int K, v4f (&acc)[4][4],
                                          bf16* sA, bf16* sB)
{
  const int tid  = threadIdx.x;
  const int lane = tid & 63;
  const int wave = tid >> 6;
  const int quad = lane >> 4;
  const int l15  = lane & 15;
  const int wr = (wave >> 1) * 64;
  const int wc = (wave & 1) * 64;

  const int r0 = tid >> 2, g0 = (tid & 3) ^ ((r0 >> 1) & 3);
  const int c1 = tid + 256;
  const int r1 = c1 >> 2,  g1 = (c1 & 3) ^ ((r1 >> 1) & 3);

  const bf16* a0p = A  + (size_t)r0*K + g0*8;
  const bf16* a1p = A  + (size_t)r1*K + g1*8;
  const bf16* b0p = Bp + (size_t)r0*K + g0*8;
  const bf16* b1p = Bp + (size_t)r1*K + g1*8;
  bf16* la0 = sA + tid*8;  bf16* la1 = sA + c1*8;
  bf16* lb0 = sB + tid*8;  bf16* lb1 = sB + c1*8;

  int aoff[4], boff[4];
  #pragma unroll
  for (int i = 0; i < 4; ++i) {
    int ra = wr + i*16 + l15;
    aoff[i] = (ra*4 + (quad ^ ((ra >> 1) & 3))) * 8;
    int rb = wc + i*16 + l15;
    boff[i] = (rb*4 + (quad ^ ((rb >> 1) & 3))) * 8;
  }

  for (int k0 = 0; k0 < K; k0 += 32) {
    __syncthreads();
    async16(a0p + k0, la0);
    async16(a1p + k0, la1);
    async16(b0p + k0, lb0);
    async16(b1p + k0, lb1);
    __syncthreads();
    v8s af[4], bfr[4];
    #pragma unroll
    for (int i = 0; i < 4; ++i) af[i]  = *(const v8s*)(sA + aoff[i]);
    #pragma unroll
    for (int i = 0; i < 4; ++i) bfr[i] = *(const v8s*)(sB + boff[i]);
    #pragma unroll
    for (int mi = 0; mi < 4; ++mi)
      #pragma unroll
      for (int ni = 0; ni < 4; ++ni)
        acc[mi][ni] = __builtin_amdgcn_mfma_f32_16x16x32_bf16(
            af[mi], bfr[ni], acc[mi][ni], 0, 0, 0);
  }
}

// C = A1@B1^T (+A2@B2^T) (+bias) (+add) ; dims multiples of 128; ldc=N, ld{a,b}=K
template<bool DUAL, bool HASBIAS, bool HASADD, bool OUTBF>
__global__ __launch_bounds__(256) void k_bgemm(
    const bf16* __restrict__ A1, const bf16* __restrict__ B1,
    const bf16* __restrict__ A2, const bf16* __restrict__ B2,
    const float* __restrict__ bias, const float* __restrict__ add,
    void* __restrict__ Cv, int N, int K)
{
  __shared__ bf16 sA[128*32];
  __shared__ bf16 sB[128*32];
  v4f acc[4][4];
  #pragma unroll
  for (int i = 0; i < 4; ++i)
    #pragma unroll
    for (int j = 0; j < 4; ++j) acc[i][j] = (v4f){0.f,0.f,0.f,0.f};

  const int row0 = blockIdx.y * 128, col0 = blockIdx.x * 128;
  mfma_loop(A1 + (size_t)row0*K, B1 + (size_t)col0*K, K, acc, sA, sB);
  if constexpr (DUAL)
    mfma_loop(A2 + (size_t)row0*K, B2 + (size_t)col0*K, K, acc, sA, sB);

  const int tid = threadIdx.x, lane = tid & 63, wave = tid >> 6;
  const int quad = lane >> 4, l15 = lane & 15;
  const int wr = (wave >> 1) * 64, wc = (wave & 1) * 64;

  #pragma unroll
  for (int ni = 0; ni < 4; ++ni) {
    const int col = col0 + wc + ni*16 + l15;
    float bv = 0.f;
    if constexpr (HASBIAS) bv = bias[col];
    #pragma unroll
    for (int mi = 0; mi < 4; ++mi) {
      const int rowb = row0 + wr + mi*16 + quad*4;
      #pragma unroll
      for (int reg = 0; reg < 4; ++reg) {
        const int row = rowb + reg;
        float v = acc[mi][ni][reg] + bv;
        if constexpr (HASADD) v += add[(size_t)row*N + col];
        if constexpr (OUTBF)
          ((bf16*)Cv)[(size_t)row*N + col] = __float2bfloat16(v);
        else
          ((float*)Cv)[(size_t)row*N + col] = v;
      }
    }
  }
}

// ---------------- split-bf16 sim: sim = zn@zn^T via hi*hi + hi*lo + lo*hi
__global__ __launch_bounds__(256) void k_sims(const bf16* __restrict__ znhi,
                                              const bf16* __restrict__ znlo,
                                              float* __restrict__ sim)
{
  __shared__ bf16 sAh[128*32];
  __shared__ bf16 sAl[128*32];
  __shared__ bf16 sBh[128*32];
  __shared__ bf16 sBl[128*32];

  const int zi = blockIdx.z;
  const int w  = zi % 3;
  const int bt = zi / 3;
  const int b  = bt / T_;
  const int t  = bt % T_;
  if (w > t) return;                       // masked region — never read by topk
  const int tw = t - w;
  const int arow0 = bt*M_ + blockIdx.y*128;
  const int brow0 = (b*T_ + tw)*M_ + blockIdx.x*128;

  const bf16* Ah = znhi + (size_t)arow0*D_;
  const bf16* Al = znlo + (size_t)arow0*D_;
  const bf16* Bh = znhi + (size_t)brow0*D_;
  const bf16* Bl = znlo + (size_t)brow0*D_;

  v4f acc[4][4];
  #pragma unroll
  for (int i = 0; i < 4; ++i)
    #pragma unroll
    for (int j = 0; j < 4; ++j) acc[i][j] = (v4f){0.f,0.f,0.f,0.f};

  const int tid  = threadIdx.x;
  const int lane = tid & 63;
  const int wave = tid >> 6;
  const int quad = lane >> 4;
  const int l15  = lane & 15;
  const int wr = (wave >> 1) * 64;
  const int wc = (wave & 1) * 64;

  const int r0 = tid >> 2, g0 = (tid & 3) ^ ((r0 >> 1) & 3);
  const int c1 = tid + 256;
  const int r1 = c1 >> 2,  g1 = (c1 & 3) ^ ((r1 >> 1) & 3);
  const size_t o0 = (size_t)r0*D_ + g0*8;
  const size_t o1 = (size_t)r1*D_ + g1*8;

  int aoff[4], boff[4];
  #pragma unroll
  for (int i = 0; i < 4; ++i) {
    int ra = wr + i*16 + l15;
    aoff[i] = (ra*4 + (quad ^ ((ra >> 1) & 3))) * 8;
    int rb = wc + i*16 + l15;
    boff[i] = (rb*4 + (quad ^ ((rb >> 1) & 3))) * 8;
  }

  for (int k0 = 0; k0 < D_; k0 += 32) {
    __syncthreads();
    async16(Ah + o0 + k0, sAh + tid*8);
    async16(Ah + o1 + k0, sAh + c1*8);
    async16(Al + o0 + k0, sAl + tid*8);
    async16(Al + o1 + k0, sAl + c1*8);
    async16(Bh + o0 + k0, sBh + tid*8);
    async16(Bh + o1 + k0, sBh + c1*8);
    async16(Bl + o0 + k0, sBl + tid*8);
    async16(Bl + o1 + k0, sBl + c1*8);
    __syncthreads();
    v8s ah[4], al[4], bh[4], bl[4];
    #pragma unroll
    for (int i = 0; i < 4; ++i) {
      ah[i] = *(const v8s*)(sAh + aoff[i]);
      al[i] = *(const v8s*)(sAl + aoff[i]);
      bh[i] = *(const v8s*)(sBh + boff[i]);
      bl[i] = *(const v8s*)(sBl + boff[i]);
    }
    #pragma unroll
    for (int mi = 0; mi < 4; ++mi)
      #pragma unroll
      for (int ni = 0; ni < 4; ++ni) {
        acc[mi][ni] = __builtin_amdgcn_mfma_f32_16x16x32_bf16(ah[mi], bh[ni], acc[mi][ni], 0, 0, 0);
        acc[mi][ni] = __builtin_amdgcn_mfma_f32_16x16x32_bf16(ah[mi], bl[ni], acc[mi][ni], 0, 0, 0);
        acc[mi][ni] = __builtin_amdgcn_mfma_f32_16x16x32_bf16(al[mi], bh[ni], acc[mi][ni], 0, 0, 0);
      }
  }

  float* C = sim + (size_t)bt*M_*NC_;
  const int rowbase = blockIdx.y*128 + wr;
  const int colbase = w*M_ + blockIdx.x*128 + wc;
  #pragma unroll
  for (int ni = 0; ni < 4; ++ni) {
    const int col = colbase + ni*16 + l15;
    #pragma unroll
    for (int mi = 0; mi < 4; ++mi) {
      const int rowb = rowbase + mi*16 + quad*4;
      #pragma unroll
      for (int reg = 0; reg < 4; ++reg)
        C[(size_t)(rowb+reg)*NC_ + col] = acc[mi][ni][reg];
    }
  }
}

// ---------------- fused Whh-GEMM(3 gates) + GRU epilogue, one timestep
// block: 128 mem-rows x 64 h-cols; grid (16,8) = 128 blocks
__global__ __launch_bounds__(256) void k_fgru(
    const bf16* __restrict__ membIn, const bf16* __restrict__ Whhb,
    const bf16* __restrict__ gib, const float* __restrict__ b_hh,
    float* __restrict__ mem, bf16* __restrict__ membOut,
    bf16* __restrict__ memhb, int t)
{
  __shared__ bf16 sA[128*32];
  __shared__ bf16 sB[3][64*32];

  const int row0 = blockIdx.y * 128;
  const int col0 = blockIdx.x * 64;

  v4f acc[3][4][2];
  #pragma unroll
  for (int g = 0; g < 3; ++g)
    #pragma unroll
    for (int i = 0; i < 4; ++i)
      #pragma unroll
      for (int j = 0; j < 2; ++j) acc[g][i][j] = (v4f){0.f,0.f,0.f,0.f};

  const int tid  = threadIdx.x;
  const int lane = tid & 63;
  const int wave = tid >> 6;
  const int quad = lane >> 4;
  const int l15  = lane & 15;
  const int wr = (wave >> 1) * 64;   // 0 or 64 (rows)
  const int wc = (wave & 1) * 32;    // 0 or 32 (cols)

  const int rA0 = tid >> 2, gA0 = (tid & 3) ^ ((rA0 >> 1) & 3);
  const int c1 = tid + 256;
  const int rA1 = c1 >> 2,  gA1 = (c1 & 3) ^ ((rA1 >> 1) & 3);
  const int rB = tid >> 2,  gB  = (tid & 3) ^ ((rB >> 1) & 3);

  const bf16* Ap = membIn + (size_t)row0*H_;
  const size_t aofs0 = (size_t)rA0*H_ + gA0*8;
  const size_t aofs1 = (size_t)rA1*H_ + gA1*8;
  const size_t bofs  = (size_t)(col0 + rB)*H_ + gB*8;

  int aoff[4], boff[2];
  #pragma unroll
  for (int i = 0; i < 4; ++i) {
    int ra = wr + i*16 + l15;
    aoff[i] = (ra*4 + (quad ^ ((ra >> 1) & 3))) * 8;
  }
  #pragma unroll
  for (int i = 0; i < 2; ++i) {
    int rb = wc + i*16 + l15;
    boff[i] = (rb*4 + (quad ^ ((rb >> 1) & 3))) * 8;
  }

  for (int k0 = 0; k0 < H_; k0 += 32) {
    __syncthreads();
    async16(Ap + aofs0 + k0, sA + tid*8);
    async16(Ap + aofs1 + k0, sA + c1*8);
    async16(Whhb + bofs + k0,           sB[0] + tid*8);
    async16(Whhb + 1048576 + bofs + k0, sB[1] + tid*8);
    async16(Whhb + 2097152 + bofs + k0, sB[2] + tid*8);
    __syncthreads();
    v8s af[4], bfr[3][2];
    #pragma unroll
    for (int i = 0; i < 4; ++i) af[i] = *(const v8s*)(sA + aoff[i]);
    #pragma unroll
    for (int g = 0; g < 3; ++g)
      #pragma unroll
      for (int i = 0; i < 2; ++i) bfr[g][i] = *(const v8s*)(sB[g] + boff[i]);
    #pragma unroll
    for (int g = 0; g < 3; ++g)
      #pragma unroll
      for (int mi = 0; mi < 4; ++mi)
        #pragma unroll
        for (int ni = 0; ni < 2; ++ni)
          acc[g][mi][ni] = __builtin_amdgcn_mfma_f32_16x16x32_bf16(
              af[mi], bfr[g][ni], acc[g][mi][ni], 0, 0, 0);
  }

  // GRU epilogue
  #pragma unroll
  for (int ni = 0; ni < 2; ++ni) {
    const int col = col0 + wc + ni*16 + l15;
    const float bhr = b_hh[col];
    const float bhz = b_hh[H_ + col];
    const float bhn = b_hh[2*H_ + col];
    #pragma unroll
    for (int mi = 0; mi < 4; ++mi) {
      const int rowb = row0 + wr + mi*16 + quad*4;
      #pragma unroll
      for (int reg = 0; reg < 4; ++reg) {
        const int row = rowb + reg;          // b*512 + m
        const int b = row >> 9, m = row & 511;
        const size_t btm = (size_t)((b*T_ + t)*M_ + m);
        const bf16* gp = gib + btm*(3*H_);
        float ir  = b2f(*(const short*)(gp + col));
        float iz  = b2f(*(const short*)(gp + H_ + col));
        float inn = b2f(*(const short*)(gp + 2*H_ + col));
        float hr = acc[0][mi][ni][reg] + bhr;
        float hz = acc[1][mi][ni][reg] + bhz;
        float hn = acc[2][mi][ni][reg] + bhn;
        float rg = 1.f/(1.f + expf(-(ir + hr)));
        float zg = 1.f/(1.f + expf(-(iz + hz)));
        float n  = tanhf(inn + rg*hn);
        const size_t mo = (size_t)row*H_ + col;
        float mold = mem[mo];
        float mnew = (1.f - zg)*n + zg*mold;
        mem[mo] = mnew;
        bf16 mb = __float2bfloat16(mnew);
        membOut[mo] = mb;
        memhb[btm*H_ + col] = mb;
      }
    }
  }
}

// ---------------- small kernels ----------------

// all 6 weight matrices -> contiguous bf16 (dst layout matches Wqb..Wmfb)
__global__ __launch_bounds__(256) void k_castall(
    const float* __restrict__ w0, const float* __restrict__ w1,
    const float* __restrict__ w2, const float* __restrict__ w3,
    const float* __restrict__ w4, const float* __restrict__ w5,
    bf16* __restrict__ dst)
{
  int i = blockIdx.x*256 + threadIdx.x;   // float4 index, total 2,621,440
  const float* src; int base;
  if      (i <  262144) { src = w0; base = 0; }
  else if (i <  524288) { src = w1; base = 262144; }
  else if (i <  786432) { src = w2; base = 524288; }
  else if (i < 1572864) { src = w3; base = 786432; }
  else if (i < 2359296) { src = w4; base = 1572864; }
  else                  { src = w5; base = 2359296; }
  float4 v = ((const float4*)src)[i - base];
  short4 o = make_short4(f2b(v.x), f2b(v.y), f2b(v.z), f2b(v.w));
  *(short4*)(dst + (size_t)i*4) = o;
}

__global__ __launch_bounds__(256) void k_colsum(const float* __restrict__ Wk,
                                                float* __restrict__ wk_sum) {
  int d = blockIdx.x*256 + threadIdx.x;
  float s = 0.f;
  for (int i = 0; i < D_; ++i) s += Wk[(size_t)i*D_ + d];
  wk_sum[d] = s;
}

__global__ __launch_bounds__(64) void k_s0(const float* __restrict__ z,
                                           const float* __restrict__ Wattq,
                                           float* __restrict__ s0) {
  int bt = blockIdx.x;
  const float* zr = z + (size_t)bt*M_*D_;
  float p = 0.f;
  for (int d = threadIdx.x; d < D_; d += 64) p += zr[d]*Wattq[d];
  for (int o = 32; o; o >>= 1) p += __shfl_down(p, o, 64);
  if (threadIdx.x == 0) s0[bt] = p;
}

// per z-row: cast->zb, normalize+split->znhi/znlo, kh = z.wks
__global__ __launch_bounds__(256) void k_zprep(const float* __restrict__ z,
                                               const float* __restrict__ wks,
                                               bf16* __restrict__ zb,
                                               bf16* __restrict__ znhi,
                                               bf16* __restrict__ znlo,
                                               float* __restrict__ kh) {
  int row = blockIdx.x, tid = threadIdx.x;
  const float* zr = z + (size_t)row*D_;
  int d = tid*4;
  float4 v = *(const float4*)(zr + d);

  float ss = v.x*v.x + v.y*v.y + v.z*v.z + v.w*v.w;
  for (int o=32;o;o>>=1) ss += __shfl_down(ss,o,64);
  __shared__ float ps[4];
  if ((tid&63)==0) ps[tid>>6] = ss;
  __syncthreads();
  float s = ps[0]+ps[1]+ps[2]+ps[3];
  float rn = 1.0f / fmaxf(sqrtf(s), 1e-12f);

  // zb cast
  *(short4*)(zb + (size_t)row*D_ + d) = make_short4(f2b(v.x), f2b(v.y), f2b(v.z), f2b(v.w));

  // hi/lo split of zn
  float zn[4] = {v.x*rn, v.y*rn, v.z*rn, v.w*rn};
  short hi[4], lo[4];
  #pragma unroll
  for (int j = 0; j < 4; ++j) {
    hi[j] = f2b(zn[j]);
    lo[j] = f2b(zn[j] - b2f(hi[j]));
  }
  *(short4*)(znhi + (size_t)row*D_ + d) = make_short4(hi[0],hi[1],hi[2],hi[3]);
  *(short4*)(znlo + (size_t)row*D_ + d) = make_short4(lo[0],lo[1],lo[2],lo[3]);

  // kh dot
  float4 w = *(const float4*)(wks + d);
  float p = v.x*w.x + v.y*w.y + v.z*w.z + v.w*w.w;
  for (int o=32;o;o>>=1) p += __shfl_down(p,o,64);
  __shared__ float pk[4];
  if ((tid&63)==0) pk[tid>>6] = p;
  __syncthreads();
  if (tid==0) kh[row] = pk[0]+pk[1]+pk[2]+pk[3];
}

// wave-per-row: top-8 -> att softmax -> alpha -> kbar(bf16) = sum alpha_k z_k
__global__ __launch_bounds__(256) void k_topk(
    const float* __restrict__ sim, const float* __restrict__ kh,
    const float* __restrict__ s0, const bf16* __restrict__ zb,
    bf16* __restrict__ kbarb)
{
  const int wave = threadIdx.x >> 6, l = threadIdx.x & 63;
  const int r  = blockIdx.x*4 + wave;
  const int bt = r >> 9, m = r & 511;
  const int b  = bt >> 3, t = bt & 7;
  const float* srow = sim + (size_t)bt*M_*NC_ + (size_t)m*NC_;
  const int limit = (t >= 2) ? NC_ : ((t == 1) ? 2*M_ : M_);

  float v[24];
  #pragma unroll
  for (int j = 0; j < 24; ++j) {
    int i = j*64 + l;
    v[j] = (i < limit) ? srow[i] : -INFINITY;
  }

  float selv[KNN]; int seli[KNN];
  #pragma unroll
  for (int k = 0; k < KNN; ++k) {
    float bv = v[0]; int bj = 0;
    #pragma unroll
    for (int j = 1; j < 24; ++j)
      if (v[j] > bv) { bv = v[j]; bj = j; }     // strict > keeps min index in-lane
    int bi = bj*64 + l;
    #pragma unroll
    for (int o = 1; o < 64; o <<= 1) {
      float ov = __shfl_xor(bv, o, 64);
      int   oi = __shfl_xor(bi, o, 64);
      if (ov > bv || (ov == bv && oi < bi)) { bv = ov; bi = oi; }
    }
    selv[k] = bv; seli[k] = bi;
    if ((bi & 63) == l) {
      int jj = bi >> 6;
      #pragma unroll
      for (int j = 0; j < 24; ++j) if (j == jj) v[j] = -INFINITY;
    }
  }

  float khv = 0.f;
  if (l < KNN) {
    int idx = seli[l];
    int w = idx >> 9, n = idx & 511;
    int tt = t - w;
    khv = kh[(b*T_ + tt)*M_ + n];
  }
  float s0v = s0[bt];
  float att[KNN], mx = -INFINITY;
  #pragma unroll
  for (int k = 0; k < KNN; ++k) { att[k] = s0v * __shfl(khv, k, 64); mx = fmaxf(mx, att[k]); }
  float den = 0.f;
  #pragma unroll
  for (int k = 0; k < KNN; ++k) { att[k] = expf(att[k]-mx); den += att[k]; }
  float rden = 1.0f/den;
  float alpha[KNN];
  #pragma unroll
  for (int k = 0; k < KNN; ++k) alpha[k] = 0.5f*selv[k] + 0.5f*att[k]*rden;

  const int d0 = l*16;
  float o[16];
  #pragma unroll
  for (int e = 0; e < 16; ++e) o[e] = 0.f;
  #pragma unroll
  for (int k = 0; k < KNN; ++k) {
    int idx = seli[k];
    int w = idx >> 9, n = idx & 511;
    int tt = t - w;
    const bf16* zp = zb + ((size_t)((b*T_ + tt)*M_ + n))*D_ + d0;
    v8s z0 = *(const v8s*)zp;
    v8s z1 = *(const v8s*)(zp + 8);
    float al = alpha[k];
    #pragma unroll
    for (int e = 0; e < 8; ++e) {
      o[e]   = fmaf(al, b2f(z0[e]), o[e]);
      o[8+e] = fmaf(al, b2f(z1[e]), o[8+e]);
    }
  }
  bf16* kp = kbarb + (size_t)r*D_ + d0;
  short outv[16];
  #pragma unroll
  for (int e = 0; e < 16; ++e) outv[e] = f2b(o[e]);
  *(v8s*)kp       = *(v8s*)outv;
  *(v8s*)(kp + 8) = *(v8s*)(outv + 8);
}

// LN: bf16 in -> bf16 out
__global__ __launch_bounds__(256) void k_ln(const bf16* __restrict__ X,
                                            const float* __restrict__ lw,
                                            const float* __restrict__ lb,
                                            bf16* __restrict__ Xb) {
  int r = blockIdx.x, tid = threadIdx.x;
  int d = tid*4;
  short4 sv = *(const short4*)(X + (size_t)r*D_ + d);
  float v0 = b2f(sv.x), v1 = b2f(sv.y), v2 = b2f(sv.z), v3 = b2f(sv.w);
  float s  = v0+v1+v2+v3;
  float ss = v0*v0+v1*v1+v2*v2+v3*v3;
  for (int o=32;o;o>>=1){ s += __shfl_down(s,o,64); ss += __shfl_down(ss,o,64); }
  __shared__ float rs[4], rss[4];
  if ((tid&63)==0){ rs[tid>>6]=s; rss[tid>>6]=ss; }
  __syncthreads();
  float mu  = (rs[0]+rs[1]+rs[2]+rs[3]) * (1.f/D_);
  float var = (rss[0]+rss[1]+rss[2]+rss[3]) * (1.f/D_) - mu*mu;
  float rstd = rsqrtf(var + 1e-5f);
  float4 w  = *(const float4*)(lw+d);
  float4 bb = *(const float4*)(lb+d);
  short4 o = make_short4(
      f2b((v0-mu)*rstd*w.x + bb.x), f2b((v1-mu)*rstd*w.y + bb.y),
      f2b((v2-mu)*rstd*w.z + bb.z), f2b((v3-mu)*rstd*w.w + bb.w));
  *(short4*)(Xb + (size_t)r*D_ + d) = o;
}

extern "C" void kernel_launch(void* const* d_in, const int* in_sizes, int n_in,
                              void* d_out, int out_size, void* d_ws, size_t ws_size,
                              hipStream_t stream) {
  (void)in_sizes; (void)n_in; (void)out_size; (void)ws_size;
  const float* z      = (const float*)d_in[0];
  const float* Wq     = (const float*)d_in[1];
  const float* Wv     = (const float*)d_in[2];
  const float* Wout   = (const float*)d_in[3];
  const float* ln_w   = (const float*)d_in[4];
  const float* ln_b   = (const float*)d_in[5];
  const float* Watt_q = (const float*)d_in[6];
  const float* Watt_k = (const float*)d_in[7];
  const float* W_ih   = (const float*)d_in[8];
  const float* W_hh   = (const float*)d_in[9];
  const float* b_ih   = (const float*)d_in[10];
  const float* b_hh   = (const float*)d_in[11];
  const float* W_mf   = (const float*)d_in[12];
  const float* b_mf   = (const float*)d_in[13];
  float* out = (float*)d_out;
  float* ws  = (float*)d_ws;

  // workspace (float offsets), region0 time-multiplexed:
  //   sim f32 (12.58M f) -> XB0 bf16 (4.19M f) -> GIb bf16 (12.58M f)
  float* sim   = ws;
  bf16*  XB0   = (bf16*)ws;
  bf16*  GIb   = (bf16*)ws;
  float* mem   = ws + 12582912;             // 1,048,576 f
  bf16*  membA = (bf16*)(ws + 13631488);    // 1,048,576 bf16
  bf16*  membB = (bf16*)(ws + 14155776);    // 1,048,576 bf16
  bf16*  znhi  = (bf16*)(ws + 14680064);    // 8,388,608 bf16 — Xb aliases (dead post-sims)
  bf16*  Xb    = znhi;
  bf16*  zb    = (bf16*)(ws + 18874368);    // 8,388,608 bf16
  bf16*  kbarb = (bf16*)(ws + 23068672);    // 8,388,608 bf16 (alias INPb)
  bf16*  INPb  = kbarb;
  bf16*  memhb = (bf16*)(ws + 27262976);    // 8,388,608 bf16 — znlo aliases (dead post-sims)
  bf16*  znlo  = memhb;
  bf16*  Wqb   = (bf16*)(ws + 31457280);    // contiguous: Wq,Wv,Wout,Wih,Whh,Wmf
  bf16*  Wvb   = Wqb + 1048576;
  bf16*  Woutb = Wqb + 2097152;
  bf16*  Wihb  = Wqb + 3145728;
  bf16*  Whhb  = Wqb + 6291456;
  bf16*  Wmfb  = Wqb + 9437184;
  float* wks   = ws + 36700160;             // 1024
  float* s0    = ws + 36701184;             // 16
  float* kh    = ws + 36701200;             // 8192
  // end ~36.71M floats ≈ 147 MiB

  k_castall<<<dim3(10240), dim3(256), 0, stream>>>(Wq, Wv, Wout, W_ih, W_hh, W_mf, Wqb);
  k_colsum <<<dim3(4),     dim3(256), 0, stream>>>(Watt_k, wks);
  k_s0     <<<dim3(16),    dim3(64),  0, stream>>>(z, Watt_q, s0);
  k_zprep  <<<dim3(8192),  dim3(256), 0, stream>>>(z, wks, zb, znhi, znlo, kh);

  // sim via error-compensated bf16 MFMA (hi*hi + hi*lo + lo*hi ~ fp32 to ~1e-7)
  k_sims<<<dim3(4,4,48), dim3(256), 0, stream>>>(znhi, znlo, sim);

  // wave-per-row topk + attention + kbar (bf16)
  k_topk<<<dim3(2048), dim3(256), 0, stream>>>(sim, kh, s0, zb, kbarb);

  // X = kbar@Wv^T + z@Wq^T  (bf16 out)
  k_bgemm<true,false,false,true><<<dim3(8,64), dim3(256), 0, stream>>>(
      kbarb, Wvb, zb, Wqb, nullptr, nullptr, XB0, D_, D_);

  // LN -> Xb (bf16)
  k_ln<<<dim3(8192), dim3(256), 0, stream>>>(XB0, ln_w, ln_b, Xb);

  // INP = X@Wout^T -> bf16
  k_bgemm<false,false,false,true><<<dim3(8,64), dim3(256), 0, stream>>>(
      Xb, Woutb, nullptr, nullptr, nullptr, nullptr, INPb, D_, D_);

  // GI = INP@W_ih^T + b_ih -> bf16 (overlays region0)
  k_bgemm<false,true,false,true><<<dim3(24,64), dim3(256), 0, stream>>>(
      INPb, Wihb, nullptr, nullptr, b_ih, nullptr, GIb, 3*H_, D_);

  hipMemsetAsync(mem,   0, (size_t)1048576*sizeof(float), stream);
  hipMemsetAsync(membA, 0, (size_t)1048576*sizeof(bf16),  stream);

  for (int t = 0; t < T_; ++t) {
    const bf16* min_ = (t & 1) ? membB : membA;
    bf16*       mout = (t & 1) ? membA : membB;
    k_fgru<<<dim3(16,8), dim3(256), 0, stream>>>(
        min_, Whhb, GIb, b_hh, mem, mout, memhb, t);
  }

  // OUT = z + memh@W_mf^T + b_mf  (single flat 8192x1024 GEMM)
  k_bgemm<false,true,true,false><<<dim3(8,64), dim3(256), 0, stream>>>(
      memhb, Wmfb, nullptr, nullptr, b_mf, z, out, D_, H_);

  hipMemcpyAsync(out + (size_t)B_*T_*M_*D_, mem, (size_t)1048576*sizeof(float),
                 hipMemcpyDeviceToDevice, stream);
}